// Round 1
// baseline (1689.118 us; speedup 1.0000x reference)
//
#include <hip/hip_runtime.h>
#include <stdint.h>
#include <math.h>

// RegularizedSSM: spectral-norm(W_A,W_B,W_C) -> xb = x Bn^T -> Blelloch scan over t
// (h_t = An h_{t-1} + xb_t) -> ys = hs Cn^T.  Outputs: [ys | hs] fp32.
//
// B=32, T=1024, H=1024.  Scan done as work-efficient Blelloch tree over t using
// powers An^(2^d) (bf16), fp32 additive spine in the d_out hs region.

typedef unsigned short us;
typedef float  floatx4 __attribute__((ext_vector_type(4)));
typedef short  shortx8 __attribute__((ext_vector_type(8)));

#define HDIM 1024
#define MALL 32768   // B*T

__device__ __forceinline__ us f2bf(float f) {
  union { float f; unsigned u; } v; v.f = f;
  unsigned u = v.u;
  return (us)((u + 0x7FFFu + ((u >> 16) & 1u)) >> 16);   // RNE
}
__device__ __forceinline__ float bf2f(us h) {
  union { float f; unsigned u; } v; v.u = ((unsigned)h) << 16;
  return v.f;
}

// ---------------- spectral norm (fp32) ----------------
__global__ void k_init_u(float* u) {
  int i = blockIdx.x * 256 + threadIdx.x;
  if (i < 3 * 1024) u[i] = 0.03125f;   // 1/sqrt(1024)
}

// v_part = W^T (u/||u||), split over 8 j-chunks. grid (4 i-tiles, 8 j-chunks, 3 mats)
__global__ void k_mv1(const float* __restrict__ WA, const float* __restrict__ WB,
                      const float* __restrict__ WC, const float* __restrict__ u,
                      float* __restrict__ vparts) {
  int mz = blockIdx.z;
  const float* W = mz == 0 ? WA : (mz == 1 ? WB : WC);
  const float* um = u + mz * 1024;
  int tid = threadIdx.x;
  __shared__ float red[256];
  float s = 0.f;
  for (int i = tid; i < 1024; i += 256) { float a = um[i]; s += a * a; }
  red[tid] = s; __syncthreads();
  for (int o = 128; o > 0; o >>= 1) { if (tid < o) red[tid] += red[tid + o]; __syncthreads(); }
  float su = 1.0f / sqrtf(red[0] + 1e-24f);
  int i = blockIdx.x * 256 + tid;
  int j0 = blockIdx.y * 128;
  float acc = 0.f;
  for (int j = j0; j < j0 + 128; ++j) acc = fmaf(W[(size_t)j * 1024 + i], um[j], acc);
  vparts[((size_t)mz * 8 + blockIdx.y) * 1024 + i] = acc * su;
}

// u = W (v/||v||), v = sum of 8 parts. grid (64 row-tiles, 3 mats), 4 waves * 4 rows
__global__ void k_mv2(const float* __restrict__ WA, const float* __restrict__ WB,
                      const float* __restrict__ WC, const float* __restrict__ vparts,
                      float* __restrict__ u) {
  int mz = blockIdx.y;
  const float* W = mz == 0 ? WA : (mz == 1 ? WB : WC);
  const float* vp = vparts + (size_t)mz * 8192;
  __shared__ float vs[1024];
  __shared__ float red[256];
  int tid = threadIdx.x;
  float s = 0.f;
  for (int i = tid; i < 1024; i += 256) {
    float a = vp[i] + vp[1024 + i] + vp[2048 + i] + vp[3072 + i]
            + vp[4096 + i] + vp[5120 + i] + vp[6144 + i] + vp[7168 + i];
    vs[i] = a; s += a * a;
  }
  red[tid] = s; __syncthreads();
  for (int o = 128; o > 0; o >>= 1) { if (tid < o) red[tid] += red[tid + o]; __syncthreads(); }
  float sv = 1.0f / sqrtf(red[0] + 1e-24f);
  int wave = tid >> 6, lane = tid & 63;
  for (int rr = 0; rr < 4; ++rr) {
    int j = blockIdx.x * 16 + wave * 4 + rr;
    const float* Wr = W + (size_t)j * 1024;
    float acc = 0.f;
    for (int i = lane; i < 1024; i += 64) acc = fmaf(Wr[i], vs[i], acc);
    #pragma unroll
    for (int o = 32; o > 0; o >>= 1) acc += __shfl_down(acc, o, 64);
    if (lane == 0) u[mz * 1024 + j] = acc * sv;
  }
}

// rsig[m] = 1/||v_raw_final||  (sigma = ||W^T u|| for normalized u)
__global__ void k_sigma(const float* __restrict__ vparts, float* __restrict__ rsig) {
  __shared__ float red[256];
  int tid = threadIdx.x;
  for (int m = 0; m < 3; ++m) {
    const float* vp = vparts + (size_t)m * 8192;
    float s = 0.f;
    for (int i = tid; i < 1024; i += 256) {
      float a = vp[i] + vp[1024 + i] + vp[2048 + i] + vp[3072 + i]
              + vp[4096 + i] + vp[5120 + i] + vp[6144 + i] + vp[7168 + i];
      s += a * a;
    }
    red[tid] = s; __syncthreads();
    for (int o = 128; o > 0; o >>= 1) { if (tid < o) red[tid] += red[tid + o]; __syncthreads(); }
    if (tid == 0) rsig[m] = 1.0f / sqrtf(red[0] + 1e-24f);
    __syncthreads();
  }
}

// ---------------- casts ----------------
// An|Bn|Cn contiguous dst; 786432 float4's total
__global__ void k_cast_mats(const float* __restrict__ WA, const float* __restrict__ WB,
                            const float* __restrict__ WC, const float* __restrict__ rsig,
                            us* __restrict__ dst) {
  int idx = blockIdx.x * 256 + threadIdx.x;
  if (idx >= 786432) return;
  int m = idx >> 18;
  const float* W = m == 0 ? WA : (m == 1 ? WB : WC);
  float rs = rsig[m];
  float4 v = ((const float4*)W)[idx & 262143];
  unsigned lo = f2bf(v.x * rs) | ((unsigned)f2bf(v.y * rs) << 16);
  unsigned hi = f2bf(v.z * rs) | ((unsigned)f2bf(v.w * rs) << 16);
  ((uint2*)dst)[idx] = make_uint2(lo, hi);
}

__global__ void k_cast_x(const float* __restrict__ src, us* __restrict__ dst, int n4) {
  int idx = blockIdx.x * 256 + threadIdx.x;
  int stride = gridDim.x * 256;
  for (; idx < n4; idx += stride) {
    float4 v = ((const float4*)src)[idx];
    unsigned lo = f2bf(v.x) | ((unsigned)f2bf(v.y) << 16);
    unsigned hi = f2bf(v.z) | ((unsigned)f2bf(v.w) << 16);
    ((uint2*)dst)[idx] = make_uint2(lo, hi);
  }
}

// bf16 1024x1024 transpose (for the squaring chain's B^T operand)
__global__ void k_transpose(const us* __restrict__ src, us* __restrict__ dst) {
  __shared__ us t[32][33];
  int bx = blockIdx.x * 32, by = blockIdx.y * 32;
  int tx = threadIdx.x & 31, ty = threadIdx.x >> 5;
  for (int r = ty; r < 32; r += 8)
    t[r][tx] = src[(size_t)(by + r) * 1024 + bx + tx];
  __syncthreads();
  for (int r = ty; r < 32; r += 8)
    dst[(size_t)(bx + r) * 1024 + by + tx] = t[tx][r];
}

// ---------------- the GEMM: C[m,n] = sum_k Aop[m,k]*B[n,k] (+acc-init) ----------------
// Row mapping for scan-tree gathers:  j = m & (cnt-1); b = m >> cnt_log;
//   rC = b*1024 + ((j+1)<<stride_log)-1;  Aop rows at rC-delta_a, acc rows rC-delta_acc,
//   outputs at rC, copy16 (down-sweep prefix pass-down) to rC-delta_copy with value Aop[rC].
template <int TILE>
__global__ __launch_bounds__(256, 2)
void k_gemm(const us* __restrict__ Abf, const us* __restrict__ Bmat,
            const float* __restrict__ AccF, const us* __restrict__ AccH,
            float* __restrict__ Out32, us* __restrict__ Out16, us* __restrict__ Out16b,
            us* __restrict__ Copy16,
            int M, int stride_log, int delta_a, int delta_acc, int delta_copy,
            int accmode /*0 zero,1 fp32,2 bf16*/, int zero_aop) {
  constexpr int BK = 32;
  constexpr int WT = TILE / 2;   // wave tile
  constexpr int NT = WT / 16;    // mfma tiles per wave dim
  constexpr int QA = TILE / 64;  // global_load_lds insts per thread per operand

  __shared__ us ldsA[TILE * BK];
  __shared__ us ldsB[TILE * BK];

  const int tid = threadIdx.x;
  const int wave = tid >> 6, lane = tid & 63;
  const int wr = wave >> 1, wc = wave & 1;
  const int lr = lane & 15, g = lane >> 4;
  const int m0 = blockIdx.x * TILE, n0 = blockIdx.y * TILE;

  const int cnt_log = 10 - stride_log;
  const int cnt_mask = (1 << cnt_log) - 1;
  auto rowC = [&](int m) -> int {
    int j = m & cnt_mask, b = m >> cnt_log;
    return (b << 10) + (((j + 1) << stride_log) - 1);
  };

  floatx4 acc[NT][NT];
  if (accmode == 0) {
    #pragma unroll
    for (int i = 0; i < NT; ++i)
      #pragma unroll
      for (int j = 0; j < NT; ++j) acc[i][j] = (floatx4)(0.0f);
  } else {
    #pragma unroll
    for (int ii = 0; ii < NT; ++ii) {
      #pragma unroll
      for (int r = 0; r < 4; ++r) {
        int m = m0 + wr * WT + ii * 16 + g * 4 + r;
        if (m >= M) m = M - 1;
        size_t rowoff = (size_t)(rowC(m) - delta_acc) * HDIM;
        #pragma unroll
        for (int jj = 0; jj < NT; ++jj) {
          int col = n0 + wc * WT + jj * 16 + lr;
          acc[ii][jj][r] = (accmode == 1) ? AccF[rowoff + col] : bf2f(AccH[rowoff + col]);
        }
      }
    }
  }

  if (!zero_aop) {
    // staging source offsets: chunk -> (row i, lds slot c') with xor swizzle so
    // ds_read_b128 fragment reads are 2-way-per-bank (free, m136).
    size_t abase[QA], bbase[QA];
    #pragma unroll
    for (int q = 0; q < QA; ++q) {
      int chunk = tid + q * 256;
      int i = chunk >> 2;
      int c = (chunk & 3) ^ ((i >> 1) & 3);
      int m = m0 + i; if (m >= M) m = M - 1;
      abase[q] = (size_t)(rowC(m) - delta_a) * HDIM + c * 8;
      bbase[q] = (size_t)(n0 + i) * HDIM + c * 8;
    }
    for (int k0 = 0; k0 < HDIM; k0 += BK) {
      __syncthreads();
      #pragma unroll
      for (int q = 0; q < QA; ++q) {
        __builtin_amdgcn_global_load_lds(
            (const __attribute__((address_space(1))) void*)(Abf + abase[q] + k0),
            (__attribute__((address_space(3))) void*)(ldsA + (wave * 64 + q * 256) * 8),
            16, 0, 0);
        __builtin_amdgcn_global_load_lds(
            (const __attribute__((address_space(1))) void*)(Bmat + bbase[q] + k0),
            (__attribute__((address_space(3))) void*)(ldsB + (wave * 64 + q * 256) * 8),
            16, 0, 0);
      }
      __syncthreads();
      shortx8 af[NT], bfv[NT];
      #pragma unroll
      for (int ii = 0; ii < NT; ++ii) {
        int ra = wr * WT + ii * 16 + lr;
        af[ii] = *(const shortx8*)(ldsA + ra * BK + ((g ^ ((ra >> 1) & 3)) * 8));
        int rb = wc * WT + ii * 16 + lr;
        bfv[ii] = *(const shortx8*)(ldsB + rb * BK + ((g ^ ((rb >> 1) & 3)) * 8));
      }
      #pragma unroll
      for (int ii = 0; ii < NT; ++ii)
        #pragma unroll
        for (int jj = 0; jj < NT; ++jj)
          acc[ii][jj] = __builtin_amdgcn_mfma_f32_16x16x32_bf16(af[ii], bfv[jj], acc[ii][jj], 0, 0, 0);
    }
  }

  // epilogue: C/D layout col = lane&15, row = (lane>>4)*4 + reg
  #pragma unroll
  for (int ii = 0; ii < NT; ++ii) {
    #pragma unroll
    for (int r = 0; r < 4; ++r) {
      int m = m0 + wr * WT + ii * 16 + g * 4 + r;
      if (m >= M) continue;
      size_t rowoff = (size_t)rowC(m) * HDIM;
      #pragma unroll
      for (int jj = 0; jj < NT; ++jj) {
        int col = n0 + wc * WT + jj * 16 + lr;
        float v = acc[ii][jj][r];
        if (Copy16) {
          us pv = zero_aop ? (us)0 : Abf[rowoff + col];
          Copy16[(size_t)(rowC(m) - delta_copy) * HDIM + col] = pv;
        }
        if (Out32)  Out32[rowoff + col] = v;
        if (Out16)  Out16[rowoff + col] = f2bf(v);
        if (Out16b) Out16b[rowoff + col] = f2bf(v);
      }
    }
  }
}

// ---------------- launch ----------------
extern "C" void kernel_launch(void* const* d_in, const int* in_sizes, int n_in,
                              void* d_out, int out_size, void* d_ws, size_t ws_size,
                              hipStream_t stream) {
  const float* x  = (const float*)d_in[0];
  const float* WA = (const float*)d_in[1];
  const float* WB = (const float*)d_in[2];
  const float* WC = (const float*)d_in[3];

  float* ys = (float*)d_out;                     // [32768,1024]
  float* U  = ys + (size_t)MALL * HDIM;          // hs region doubles as fp32 scan state

  char* wsb = (char*)d_ws;
  float* rsig   = (float*)(wsb);                 // 3 floats
  float* ubuf   = (float*)(wsb + 4096);          // 3*1024
  float* vparts = (float*)(wsb + 20480);         // 3*8*1024
  us* An = (us*)(wsb + 151552);                  // An,Bn,Cn contiguous (cast target)
  us* Bn = An + 1048576;
  us* Cn = Bn + 1048576;
  us* PT = Cn + 1048576;                         // transpose scratch
  us* Ppow[9];
  Ppow[0] = An;
  for (int d = 1; d <= 8; ++d) Ppow[d] = PT + (size_t)d * 1048576;
  us* Ubf  = (us*)(wsb + 25317376);              // 64MB  up-sweep bf16 mirror / down ping A / Hbf
  us* U0bf = Ubf + (size_t)MALL * HDIM;          // 64MB  original xb (bf16) for final apply
  us* Xbf  = U0bf + (size_t)MALL * HDIM;         // 64MB  x bf16 / down ping B (final prefixes)
  if (ws_size < 226643968ULL) return;            // need ~217MB

  auto gemm = [&](int tile, const us* A, const us* B, const float* aF, const us* aH,
                  float* o32, us* o16, us* o16b, us* cp16,
                  int M, int slog, int da, int dacc, int dcp, int am, int za) {
    dim3 grid((M + tile - 1) / tile, HDIM / tile);
    if (tile == 128)
      k_gemm<128><<<grid, 256, 0, stream>>>(A, B, aF, aH, o32, o16, o16b, cp16, M, slog, da, dacc, dcp, am, za);
    else
      k_gemm<64><<<grid, 256, 0, stream>>>(A, B, aF, aH, o32, o16, o16b, cp16, M, slog, da, dacc, dcp, am, za);
  };

  // 1) spectral norms
  k_init_u<<<dim3(12), 256, 0, stream>>>(ubuf);
  for (int it = 0; it < 10; ++it) {
    k_mv1<<<dim3(4, 8, 3), 256, 0, stream>>>(WA, WB, WC, ubuf, vparts);
    k_mv2<<<dim3(64, 3), 256, 0, stream>>>(WA, WB, WC, vparts, ubuf);
  }
  k_mv1<<<dim3(4, 8, 3), 256, 0, stream>>>(WA, WB, WC, ubuf, vparts);
  k_sigma<<<1, 256, 0, stream>>>(vparts, rsig);

  // 2) casts (1/sigma folded in)
  k_cast_mats<<<dim3(3072), 256, 0, stream>>>(WA, WB, WC, rsig, An);
  k_cast_x<<<dim3(8192), 256, 0, stream>>>(x, Xbf, 8388608);

  // 3) power chain A^(2^d), d=1..8 (square via B^T trick: P*P = bt(P, P^T))
  for (int d = 1; d <= 8; ++d) {
    k_transpose<<<dim3(32, 32), 256, 0, stream>>>(Ppow[d - 1], PT);
    gemm(64, Ppow[d - 1], PT, nullptr, nullptr, nullptr, Ppow[d], nullptr, nullptr,
         1024, 0, 0, 0, 0, 0, 0);
  }

  // 4) xb = x Bn^T  -> U(fp32), Ubf, U0bf
  gemm(128, Xbf, Bn, nullptr, nullptr, U, Ubf, U0bf, nullptr, MALL, 0, 0, 0, 0, 0, 0);

  // 5) Blelloch up-sweep: U[tC] = A^(2^d) U[tA] + U[tC]
  for (int d = 0; d <= 8; ++d) {
    int M = MALL >> (d + 1);
    gemm(M >= 2048 ? 128 : 64, Ubf, Ppow[d], U, nullptr, U, Ubf, nullptr, nullptr,
         M, d + 1, 1 << d, 0, 0, 1, 0);
  }

  // 6) down-sweep (prefix bf16 ping-pong; additive operand = fp32 up-sweep state)
  {
    us* PP2[2] = {Ubf, Xbf};
    for (int idx = 0; idx <= 9; ++idx) {
      int d = 9 - idx;
      int M = MALL >> (d + 1);
      const us* srcA = idx ? PP2[(idx - 1) & 1] : nullptr;   // idx 0: root prefix = 0
      us* dst = PP2[idx & 1];
      gemm(M >= 2048 ? 128 : 64, srcA, Ppow[d <= 8 ? d : 0], U, nullptr,
           nullptr, dst, nullptr, dst,
           M, d + 1, 0, 1 << d, 1 << d, 1, idx == 0 ? 1 : 0);
    }
  }

  // 7) final apply: h_t = An * p_t + xb_t  (p in Xbf, xb in U0bf) -> hs fp32 + Hbf(=Ubf)
  gemm(128, Xbf, An, nullptr, U0bf, U, Ubf, nullptr, nullptr, MALL, 0, 0, 0, 0, 2, 0);

  // 8) ys = hs Cn^T
  gemm(128, Ubf, Cn, nullptr, nullptr, ys, nullptr, nullptr, nullptr, MALL, 0, 0, 0, 0, 0, 0);
}

// Round 2
// 1539.475 us; speedup vs baseline: 1.0972x; 1.0972x over previous
//
#include <hip/hip_runtime.h>
#include <hip/hip_fp16.h>
#include <stdint.h>
#include <math.h>

// RegularizedSSM: fused spectral-norm (atomic-barrier persistent kernel) ->
// xb = x Bn^T -> Blelloch scan over t (bf16 A-op path + fp16 accumulator path)
// -> hs fp32 -> ys = hs Cn^T.   BK=64 GEMM (32 MFMA per barrier).

typedef unsigned short us;
typedef float  floatx4 __attribute__((ext_vector_type(4)));
typedef short  shortx8 __attribute__((ext_vector_type(8)));

#define HDIM 1024
#define MALL 32768   // B*T

__device__ __forceinline__ us f2bf(float f) {
  union { float f; unsigned u; } v; v.f = f;
  unsigned u = v.u;
  return (us)((u + 0x7FFFu + ((u >> 16) & 1u)) >> 16);   // RNE
}
__device__ __forceinline__ float bf2f(us h) {
  union { float f; unsigned u; } v; v.u = ((unsigned)h) << 16;
  return v.f;
}

// ---------------- fused spectral norm: 8 blocks/matrix, atomic barrier ----------------
__device__ __forceinline__ void gbar(int* bar, int idx) {
  __threadfence();     // device-scope release of this block's prior writes
  __syncthreads();
  if (threadIdx.x == 0) {
    __hip_atomic_fetch_add(&bar[idx], 1, __ATOMIC_ACQ_REL, __HIP_MEMORY_SCOPE_AGENT);
    while (__hip_atomic_load(&bar[idx], __ATOMIC_ACQUIRE, __HIP_MEMORY_SCOPE_AGENT) < 8)
      __builtin_amdgcn_s_sleep(2);
  }
  __syncthreads();
}

// grid (8, 3) x 1024 threads.  uu/vv hold RAW (unnormalized) vectors; norms folded.
__global__ void k_power(const float* __restrict__ WA, const float* __restrict__ WB,
                        const float* __restrict__ WC,
                        float* __restrict__ uu, float* __restrict__ vv,
                        float* __restrict__ rsig, int* __restrict__ bar) {
  const int m = blockIdx.y, b = blockIdx.x, tid = threadIdx.x;
  const float* W = m == 0 ? WA : (m == 1 ? WB : WC);
  float* um = uu + m * 1024;
  float* vm = vv + m * 1024;
  int* barm = bar + m * 32;
  __shared__ float red[1024];
  __shared__ float vs[1024];

  if (tid < 128) um[b * 128 + tid] = 0.03125f;   // 1/sqrt(1024)
  gbar(barm, 0);

  auto ssq_of = [&](const float* p) -> float {
    float a = p[tid];
    red[tid] = a * a; __syncthreads();
    for (int o = 512; o > 0; o >>= 1) { if (tid < o) red[tid] += red[tid + o]; __syncthreads(); }
    float r = red[0]; __syncthreads();
    return r;
  };

  const int il = tid & 127, jp = tid >> 7;   // phase A indexing
  const int jr = tid >> 3, ip = tid & 7;     // phase B indexing

  for (int it = 0; it <= 10; ++it) {
    // phase A: v_raw = W^T (u_raw/||u_raw||), block owns cols [b*128, b*128+128)
    float su = rsqrtf(ssq_of(um) + 1e-24f);
    {
      int i = b * 128 + il;
      float acc = 0.f;
      const float* Wp = W + (size_t)(jp * 128) * 1024 + i;
      #pragma unroll 4
      for (int j = 0; j < 128; ++j) acc = fmaf(Wp[(size_t)j * 1024], um[jp * 128 + j], acc);
      red[tid] = acc; __syncthreads();
      if (tid < 128) {
        float s = red[il] + red[il + 128] + red[il + 256] + red[il + 384]
                + red[il + 512] + red[il + 640] + red[il + 768] + red[il + 896];
        vm[b * 128 + il] = s * su;
      }
      __syncthreads();
    }
    gbar(barm, 1 + 2 * it);
    if (it == 10) break;
    // phase B: u_raw = W (v_raw/||v_raw||), block owns rows [b*128, ...)
    float sv = rsqrtf(ssq_of(vm) + 1e-24f);
    vs[tid] = vm[tid] * sv;
    __syncthreads();
    {
      int j = b * 128 + jr;
      const float* Wr = W + (size_t)j * 1024;
      float acc = 0.f;
      #pragma unroll 4
      for (int k = 0; k < 128; ++k) acc = fmaf(Wr[ip + 8 * k], vs[ip + 8 * k], acc);
      #pragma unroll
      for (int o = 4; o > 0; o >>= 1) acc += __shfl_down(acc, o, 8);
      if (ip == 0) um[j] = acc;
    }
    __syncthreads();
    gbar(barm, 2 + 2 * it);
  }
  // sigma = ||v_raw_final|| (u was normalized going in)
  if (b == 0) {
    float s = ssq_of(vm);
    if (tid == 0) rsig[m] = rsqrtf(s + 1e-24f);
  }
}

// ---------------- casts ----------------
__global__ void k_cast_mats(const float* __restrict__ WA, const float* __restrict__ WB,
                            const float* __restrict__ WC, const float* __restrict__ rsig,
                            us* __restrict__ dst) {
  int idx = blockIdx.x * 256 + threadIdx.x;
  if (idx >= 786432) return;
  int m = idx >> 18;
  const float* W = m == 0 ? WA : (m == 1 ? WB : WC);
  float rs = rsig[m];
  float4 v = ((const float4*)W)[idx & 262143];
  unsigned lo = f2bf(v.x * rs) | ((unsigned)f2bf(v.y * rs) << 16);
  unsigned hi = f2bf(v.z * rs) | ((unsigned)f2bf(v.w * rs) << 16);
  ((uint2*)dst)[idx] = make_uint2(lo, hi);
}

__global__ void k_cast_x(const float* __restrict__ src, us* __restrict__ dst, int n4) {
  int idx = blockIdx.x * 256 + threadIdx.x;
  int stride = gridDim.x * 256;
  for (; idx < n4; idx += stride) {
    float4 v = ((const float4*)src)[idx];
    unsigned lo = f2bf(v.x) | ((unsigned)f2bf(v.y) << 16);
    unsigned hi = f2bf(v.z) | ((unsigned)f2bf(v.w) << 16);
    ((uint2*)dst)[idx] = make_uint2(lo, hi);
  }
}

// bf16 1024x1024 transpose
__global__ void k_transpose(const us* __restrict__ src, us* __restrict__ dst) {
  __shared__ us t[32][33];
  int bx = blockIdx.x * 32, by = blockIdx.y * 32;
  int tx = threadIdx.x & 31, ty = threadIdx.x >> 5;
  for (int r = ty; r < 32; r += 8)
    t[r][tx] = src[(size_t)(by + r) * 1024 + bx + tx];
  __syncthreads();
  for (int r = ty; r < 32; r += 8)
    dst[(size_t)(bx + r) * 1024 + by + tx] = t[tx][r];
}

// ---------------- GEMM: C[m,n] = sum_k Aop[m,k]*B[n,k] (+acc-init), BK=64 ----------------
// accmode: 0 zero, 2 bf16 acc, 3 fp16 acc.
template <int TILE>
__global__ __launch_bounds__(256, 3)
void k_gemm(const us* __restrict__ Abf, const us* __restrict__ Bmat,
            const us* __restrict__ AccP,
            float* __restrict__ Out32, us* __restrict__ Out16, us* __restrict__ OutH,
            us* __restrict__ Copy16,
            int M, int stride_log, int delta_a, int delta_acc, int delta_copy,
            int accmode, int zero_aop) {
  constexpr int BK = 64;
  constexpr int WT = TILE / 2;   // wave tile
  constexpr int NT = WT / 16;    // mfma tiles per wave dim
  constexpr int QA = TILE / 32;  // 16B staging chunks per thread per operand

  __shared__ us ldsA[TILE * BK];
  __shared__ us ldsB[TILE * BK];

  const int tid = threadIdx.x;
  const int wave = tid >> 6, lane = tid & 63;
  const int wr = wave >> 1, wc = wave & 1;
  const int lr = lane & 15, g = lane >> 4;
  const int m0 = blockIdx.x * TILE, n0 = blockIdx.y * TILE;

  const int cnt_log = 10 - stride_log;
  const int cnt_mask = (1 << cnt_log) - 1;
  auto rowC = [&](int m) -> int {
    int j = m & cnt_mask, b = m >> cnt_log;
    return (b << 10) + (((j + 1) << stride_log) - 1);
  };

  floatx4 acc[NT][NT];
  if (accmode == 0) {
    #pragma unroll
    for (int i = 0; i < NT; ++i)
      #pragma unroll
      for (int j = 0; j < NT; ++j) acc[i][j] = (floatx4)(0.0f);
  } else {
    #pragma unroll
    for (int ii = 0; ii < NT; ++ii) {
      #pragma unroll
      for (int r = 0; r < 4; ++r) {
        int m = m0 + wr * WT + ii * 16 + g * 4 + r;
        if (m >= M) m = M - 1;
        size_t rowoff = (size_t)(rowC(m) - delta_acc) * HDIM;
        #pragma unroll
        for (int jj = 0; jj < NT; ++jj) {
          int col = n0 + wc * WT + jj * 16 + lr;
          us raw = AccP[rowoff + col];
          acc[ii][jj][r] = (accmode == 2) ? bf2f(raw)
                                          : __half2float(*(const __half*)&raw);
        }
      }
    }
  }

  if (!zero_aop) {
    // chunk ch = tid + q*256 -> row i = ch>>3, physical slot p = ch&7,
    // logical k-chunk c = p ^ s(i), s(i)=(i>>1)&7 (2-way-per-bank on ds_read_b128).
    size_t abase[QA], bbase[QA];
    #pragma unroll
    for (int q = 0; q < QA; ++q) {
      int ch = tid + q * 256;
      int i = ch >> 3;
      int c = (ch & 7) ^ ((i >> 1) & 7);
      int m = m0 + i; if (m >= M) m = M - 1;
      abase[q] = (size_t)(rowC(m) - delta_a) * HDIM + c * 8;
      bbase[q] = (size_t)(n0 + i) * HDIM + c * 8;
    }
    for (int k0 = 0; k0 < HDIM; k0 += BK) {
      __syncthreads();
      #pragma unroll
      for (int q = 0; q < QA; ++q) {
        __builtin_amdgcn_global_load_lds(
            (const __attribute__((address_space(1))) void*)(Abf + abase[q] + k0),
            (__attribute__((address_space(3))) void*)(ldsA + (wave * 64 + q * 256) * 8),
            16, 0, 0);
        __builtin_amdgcn_global_load_lds(
            (const __attribute__((address_space(1))) void*)(Bmat + bbase[q] + k0),
            (__attribute__((address_space(3))) void*)(ldsB + (wave * 64 + q * 256) * 8),
            16, 0, 0);
      }
      __syncthreads();
      #pragma unroll
      for (int kk = 0; kk < 2; ++kk) {
        shortx8 af[NT], bfv[NT];
        #pragma unroll
        for (int ii = 0; ii < NT; ++ii) {
          int ra = wr * WT + ii * 16 + lr;
          af[ii] = *(const shortx8*)(ldsA + ra * BK + (((kk * 4 + g) ^ ((ra >> 1) & 7)) * 8));
          int rb = wc * WT + ii * 16 + lr;
          bfv[ii] = *(const shortx8*)(ldsB + rb * BK + (((kk * 4 + g) ^ ((rb >> 1) & 7)) * 8));
        }
        #pragma unroll
        for (int ii = 0; ii < NT; ++ii)
          #pragma unroll
          for (int jj = 0; jj < NT; ++jj)
            acc[ii][jj] = __builtin_amdgcn_mfma_f32_16x16x32_bf16(af[ii], bfv[jj], acc[ii][jj], 0, 0, 0);
      }
    }
  }

  // epilogue: C/D layout col = lane&15, row = (lane>>4)*4 + reg
  #pragma unroll
  for (int ii = 0; ii < NT; ++ii) {
    #pragma unroll
    for (int r = 0; r < 4; ++r) {
      int m = m0 + wr * WT + ii * 16 + g * 4 + r;
      if (m >= M) continue;
      size_t rowoff = (size_t)rowC(m) * HDIM;
      #pragma unroll
      for (int jj = 0; jj < NT; ++jj) {
        int col = n0 + wc * WT + jj * 16 + lr;
        float v = acc[ii][jj][r];
        if (Copy16) {
          us pv = zero_aop ? (us)0 : Abf[rowoff + col];
          Copy16[(size_t)(rowC(m) - delta_copy) * HDIM + col] = pv;
        }
        if (Out32) Out32[rowoff + col] = v;
        if (Out16) Out16[rowoff + col] = f2bf(v);
        if (OutH) {
          __half hv = __float2half(v);
          OutH[rowoff + col] = *(const us*)&hv;
        }
      }
    }
  }
}

// ---------------- launch ----------------
extern "C" void kernel_launch(void* const* d_in, const int* in_sizes, int n_in,
                              void* d_out, int out_size, void* d_ws, size_t ws_size,
                              hipStream_t stream) {
  const float* x  = (const float*)d_in[0];
  const float* WA = (const float*)d_in[1];
  const float* WB = (const float*)d_in[2];
  const float* WC = (const float*)d_in[3];

  float* ys = (float*)d_out;                     // [32768,1024]
  float* U  = ys + (size_t)MALL * HDIM;          // hs region (also down-sweep ping A)
  us* U16 = (us*)U;

  char* wsb = (char*)d_ws;
  int*   bar  = (int*)(wsb);                     // 3*32 barrier counters
  float* rsig = (float*)(wsb + 2048);            // 3
  float* uu   = (float*)(wsb + 4096);            // 3*1024
  float* vv   = (float*)(wsb + 20480);           // 3*1024
  us* An = (us*)(wsb + 65536);                   // An,Bn,Cn contiguous
  us* Bn = An + 1048576;
  us* Cn = Bn + 1048576;
  us* PT = Cn + 1048576;                         // transpose scratch + powers
  us* Ppow[9];
  Ppow[0] = An;
  for (int d = 1; d <= 8; ++d) Ppow[d] = PT + (size_t)d * 1048576;
  us* Xbf  = (us*)(wsb + 25231360);              // 64MB: x bf16, then fp16 node buffer Uh
  us* Uh   = Xbf;                                //       (x dead after step 4)
  us* U0bf = Xbf + (size_t)MALL * HDIM;          // 64MB: xb bf16; later Hbf mirror
  us* Ubf  = U0bf + (size_t)MALL * HDIM;         // 64MB: up-sweep node bf16 / ping B
  if (ws_size < 226643968ULL) return;

  auto gemm = [&](int tile, const us* A, const us* B, const us* accP,
                  float* o32, us* o16, us* oH, us* cp16,
                  int M, int slog, int da, int dacc, int dcp, int am, int za) {
    dim3 grid((M + tile - 1) / tile, HDIM / tile);
    if (tile == 128)
      k_gemm<128><<<grid, 256, 0, stream>>>(A, B, accP, o32, o16, oH, cp16, M, slog, da, dacc, dcp, am, za);
    else
      k_gemm<64><<<grid, 256, 0, stream>>>(A, B, accP, o32, o16, oH, cp16, M, slog, da, dacc, dcp, am, za);
  };

  // 1) spectral norms (one persistent kernel; barrier counters zeroed per call)
  hipMemsetAsync(bar, 0, 3 * 32 * sizeof(int), stream);
  k_power<<<dim3(8, 3), 1024, 0, stream>>>(WA, WB, WC, uu, vv, rsig, bar);

  // 2) casts (1/sigma folded in)
  k_cast_mats<<<dim3(3072), 256, 0, stream>>>(WA, WB, WC, rsig, An);
  k_cast_x<<<dim3(8192), 256, 0, stream>>>(x, Xbf, 8388608);

  // 3) power chain A^(2^d), d=1..8
  for (int d = 1; d <= 8; ++d) {
    k_transpose<<<dim3(32, 32), 256, 0, stream>>>(Ppow[d - 1], PT);
    gemm(64, Ppow[d - 1], PT, nullptr, nullptr, Ppow[d], nullptr, nullptr,
         1024, 0, 0, 0, 0, 0, 0);
  }

  // 4) xb = x Bn^T -> U0bf (bf16 only)
  gemm(128, Xbf, Bn, nullptr, nullptr, U0bf, nullptr, nullptr, MALL, 0, 0, 0, 0, 0, 0);

  // 5) up-sweep: node = A^(2^d) * left + right ; bf16 nodes -> Ubf, fp16 nodes -> Uh
  for (int d = 0; d <= 8; ++d) {
    int M = MALL >> (d + 1);
    const us* srcA = (d == 0) ? U0bf : Ubf;
    const us* accP = (d == 0) ? U0bf : Uh;
    int am = (d == 0) ? 2 : 3;
    gemm(M >= 2048 ? 128 : 64, srcA, Ppow[d], accP, nullptr, Ubf, Uh, nullptr,
         M, d + 1, 1 << d, 0, 0, am, 0);
  }

  // 6) down-sweep: prefix_right = A^(2^d) prefix_par + up_left; prefix_left = prefix_par
  //    ping-pong U16 (d_out hs region) <-> Ubf; additive from Uh fp16 (U0bf bf16 at d=0)
  {
    us* PP2[2] = {U16, Ubf};        // idx even -> U16, idx odd -> Ubf; idx9 dst = Ubf
    for (int idx = 0; idx <= 9; ++idx) {
      int d = 9 - idx;
      int M = MALL >> (d + 1);
      const us* srcA = idx ? PP2[(idx - 1) & 1] : nullptr;
      us* dst = PP2[idx & 1];
      const us* accP = (d == 0) ? U0bf : Uh;
      int am = (d == 0) ? 2 : 3;
      gemm(M >= 2048 ? 128 : 64, srcA, Ppow[d], accP,
           nullptr, dst, nullptr, dst,
           M, d + 1, 0, 1 << d, 1 << d, am, idx == 0 ? 1 : 0);
    }
  }

  // 7) final apply: h_t = An * p_t + xb_t  (p in Ubf, xb in U0bf) -> hs fp32 + Hbf(->U0bf)
  gemm(128, Ubf, An, U0bf, U, U0bf, nullptr, nullptr, MALL, 0, 0, 0, 0, 2, 0);

  // 8) ys = hs Cn^T
  gemm(128, U0bf, Cn, nullptr, ys, nullptr, nullptr, nullptr, MALL, 0, 0, 0, 0, 0, 0);
}